// Round 2
// baseline (550.060 us; speedup 1.0000x reference)
//
#include <hip/hip_runtime.h>

#define B_N   32768
#define D_RGBc 512
#define D_SPDc 128
#define D_INc  640
#define Hc     256
#define Cc     7

typedef __bf16 bf16x8 __attribute__((ext_vector_type(8)));
typedef float  f32x4  __attribute__((ext_vector_type(4)));

__device__ __forceinline__ float sigmoidf_(float x) { return 1.0f / (1.0f + __expf(-x)); }

// ---------- weights: [C][K][N] f32 -> [C][N][K] bf16 (so MFMA B-frags are contiguous) ----------
__global__ void transpose_kernel(const float* __restrict__ W1, const float* __restrict__ W2,
                                 const float* __restrict__ W3,
                                 __bf16* __restrict__ w1t, __bf16* __restrict__ w2t,
                                 __bf16* __restrict__ w3t)
{
    int m = blockIdx.z;                 // 0..6 W1, 7..13 W2, 14..20 W3
    const float* src; __bf16* dst; int K;
    if (m < 7)       { src = W1 + (size_t)m * D_INc * Hc;      dst = w1t + (size_t)m * Hc * D_INc;      K = D_INc; }
    else if (m < 14) { int c = m - 7;  src = W2 + (size_t)c * Hc * Hc; dst = w2t + (size_t)c * Hc * Hc; K = Hc; }
    else             { int c = m - 14; src = W3 + (size_t)c * Hc * Hc; dst = w3t + (size_t)c * Hc * Hc; K = Hc; }
    int k0 = blockIdx.y * 32;
    if (k0 >= K) return;
    int n0 = blockIdx.x * 32;
    __shared__ float tile[32][33];
    int tx = threadIdx.x, ty = threadIdx.y;     // 32 x 8
    #pragma unroll
    for (int i = 0; i < 32; i += 8)
        tile[ty + i][tx] = src[(size_t)(k0 + ty + i) * Hc + n0 + tx];
    __syncthreads();
    #pragma unroll
    for (int i = 0; i < 32; i += 8)
        dst[(size_t)(n0 + ty + i) * K + k0 + tx] = (__bf16)tile[tx][ty + i];
}

// ---------- speed MLP (1->128->128->128 tanh) + concat into x[B][640] bf16 ----------
__launch_bounds__(128)
__global__ void build_x_kernel(const float* __restrict__ rgb, const float* __restrict__ spd,
    const float* __restrict__ sW1, const float* __restrict__ sb1,
    const float* __restrict__ sW2, const float* __restrict__ sb2,
    const float* __restrict__ sW3, const float* __restrict__ sb3,
    __bf16* __restrict__ xb)
{
    __shared__ float s0[D_SPDc], s1buf[D_SPDc];
    int j = threadIdx.x;                       // 128 threads, one row per block-iteration
    for (int row = blockIdx.x; row < B_N; row += gridDim.x) {
        float sv = spd[row];
        s0[j] = tanhf(sv * sW1[j] + sb1[j]);
        __syncthreads();
        float a = sb2[j];
        #pragma unroll 8
        for (int k = 0; k < D_SPDc; ++k) a = fmaf(s0[k], sW2[k * D_SPDc + j], a);
        s1buf[j] = tanhf(a);
        __syncthreads();
        a = sb3[j];
        #pragma unroll 8
        for (int k = 0; k < D_SPDc; ++k) a = fmaf(s1buf[k], sW3[k * D_SPDc + j], a);
        float s3 = tanhf(a);
        __bf16* xr = xb + (size_t)row * D_INc;
        const float* rr = rgb + (size_t)row * D_RGBc;
        #pragma unroll
        for (int i = 0; i < 4; ++i) xr[j + 128 * i] = (__bf16)rr[j + 128 * i];
        xr[D_RGBc + j] = (__bf16)s3;
        __syncthreads();                       // uniform trip count: safe
    }
}

// ---------- per-block histogram of cmd ----------
__global__ void hist_kernel(const int* __restrict__ cmd, int* __restrict__ hist_part)
{
    __shared__ int h[Cc];
    if (threadIdx.x < Cc) h[threadIdx.x] = 0;
    __syncthreads();
    for (int i = blockIdx.x * 256 + threadIdx.x; i < B_N; i += 64 * 256)
        atomicAdd(&h[cmd[i]], 1);
    __syncthreads();
    if (threadIdx.x < Cc) hist_part[blockIdx.x * Cc + threadIdx.x] = h[threadIdx.x];
}

// ---------- reduce partials -> cnt[0..6], offs[8..14], fill[16..22] ----------
__global__ void scan_kernel(const int* __restrict__ hist_part, int* __restrict__ cof)
{
    int l = threadIdx.x;                       // 64
    int v[Cc];
    #pragma unroll
    for (int c = 0; c < Cc; ++c) v[c] = hist_part[l * Cc + c];
    #pragma unroll
    for (int c = 0; c < Cc; ++c)
        for (int m = 1; m < 64; m <<= 1) v[c] += __shfl_xor(v[c], m);
    if (l == 0) {
        int run = 0;
        for (int c = 0; c < Cc; ++c) {
            cof[c] = v[c]; cof[8 + c] = run; cof[16 + c] = run; run += v[c];
        }
    }
}

// ---------- scatter row indices bucketed by cmd (ballot-aggregated atomics) ----------
__global__ void scatter_kernel(const int* __restrict__ cmd, int* __restrict__ cof,
                               int* __restrict__ rowlist)
{
    int i = blockIdx.x * 256 + threadIdx.x;    // grid covers B exactly
    int lane = threadIdx.x & 63;
    int cv = cmd[i];
    #pragma unroll
    for (int c = 0; c < Cc; ++c) {
        unsigned long long mask = __ballot(cv == c);
        if (mask == 0ull) continue;
        int leader = __ffsll((unsigned long long)mask) - 1;
        int basep = 0;
        if (lane == leader) basep = atomicAdd(&cof[16 + c], (int)__popcll(mask));
        basep = __shfl(basep, leader);
        if (cv == c) {
            int rank = (int)__popcll(mask & ((1ull << lane) - 1ull));
            rowlist[basep + rank] = i;
        }
    }
}

// ---------- helpers for the branch MLP ----------
__device__ __forceinline__ void mfma_layer_lds(const char* hs_in, const __bf16* wt,
                                               int wave, int l15, int lg, f32x4 acc[16])
{
    int lrow = wave * 16 + l15;
    int sw = (lrow & 7) << 4;                  // XOR swizzle: kills 16-way bank conflict
    for (int k0 = 0; k0 < Hc; k0 += 32) {
        bf16x8 a = *reinterpret_cast<const bf16x8*>(hs_in + lrow * 512 + (((k0 + 8 * lg) * 2) ^ sw));
        #pragma unroll
        for (int nt = 0; nt < 16; ++nt) {
            bf16x8 b = *reinterpret_cast<const bf16x8*>(wt + (size_t)(nt * 16 + l15) * Hc + k0 + 8 * lg);
            acc[nt] = __builtin_amdgcn_mfma_f32_16x16x32_bf16(a, b, acc[nt], 0, 0, 0);
        }
    }
}

__device__ __forceinline__ void store_act_lds(char* hs_out, const float* bias,
                                              int wave, int l15, int lg, const f32x4 acc[16])
{
    #pragma unroll
    for (int nt = 0; nt < 16; ++nt) {
        int col = nt * 16 + l15;
        float bv = bias[col];
        #pragma unroll
        for (int r = 0; r < 4; ++r) {
            int rowl = wave * 16 + lg * 4 + r;     // verified C/D layout: row=(lane>>4)*4+reg
            float v = sigmoidf_(acc[nt][r] + bv);
            *(__bf16*)(hs_out + rowl * 512 + ((col * 2) ^ ((rowl & 7) << 4))) = (__bf16)v;
        }
    }
}

// ---------- main: per block = 64 gathered rows of one branch ----------
__launch_bounds__(256)
__global__ void branch_mlp_kernel(const __bf16* __restrict__ xb,
    const __bf16* __restrict__ w1t, const __bf16* __restrict__ w2t, const __bf16* __restrict__ w3t,
    const float* __restrict__ b1, const float* __restrict__ b2, const float* __restrict__ b3,
    const float* __restrict__ hWb, const float* __restrict__ hbb,
    const float* __restrict__ hWs, const float* __restrict__ hbs,
    const float* __restrict__ hWt, const float* __restrict__ hbt,
    const int* __restrict__ cof, const int* __restrict__ rowlist,
    float* __restrict__ out)
{
    int c = blockIdx.y;
    int n_c = cof[c];
    int row0 = blockIdx.x * 64;
    if (row0 >= n_c) return;
    int base = cof[8 + c];
    int tid = threadIdx.x;
    int wave = tid >> 6, lane = tid & 63, l15 = lane & 15, lg = lane >> 4;

    __shared__ char hsA[64 * 512];
    __shared__ char hsB[64 * 512];

    int gA = row0 + wave * 16 + l15;
    int rowA = rowlist[base + (gA < n_c ? gA : 0)];   // clamp: dup row, result discarded
    const __bf16* xrow = xb + (size_t)rowA * D_INc + 8 * lg;

    f32x4 acc[16];
    const f32x4 zero = {0.f, 0.f, 0.f, 0.f};
    #pragma unroll
    for (int nt = 0; nt < 16; ++nt) acc[nt] = zero;

    // layer 1: K=640, A from global (gathered rows), B from transposed weights
    const __bf16* w1c = w1t + (size_t)c * Hc * D_INc + (size_t)l15 * D_INc + 8 * lg;
    for (int k0 = 0; k0 < D_INc; k0 += 32) {
        bf16x8 a = *reinterpret_cast<const bf16x8*>(xrow + k0);
        #pragma unroll
        for (int nt = 0; nt < 16; ++nt) {
            bf16x8 b = *reinterpret_cast<const bf16x8*>(w1c + (size_t)nt * 16 * D_INc + k0);
            acc[nt] = __builtin_amdgcn_mfma_f32_16x16x32_bf16(a, b, acc[nt], 0, 0, 0);
        }
    }
    store_act_lds(hsA, b1 + c * Hc, wave, l15, lg, acc);
    __syncthreads();

    // layer 2
    #pragma unroll
    for (int nt = 0; nt < 16; ++nt) acc[nt] = zero;
    mfma_layer_lds(hsA, w2t + (size_t)c * Hc * Hc, wave, l15, lg, acc);
    store_act_lds(hsB, b2 + c * Hc, wave, l15, lg, acc);
    __syncthreads();

    // layer 3
    #pragma unroll
    for (int nt = 0; nt < 16; ++nt) acc[nt] = zero;
    mfma_layer_lds(hsB, w3t + (size_t)c * Hc * Hc, wave, l15, lg, acc);

    // heads: in-register dot with 16-lane shuffle reduce
    const float* b3c = b3 + c * Hc;
    const float* wbp = hWb + c * Hc;
    const float* wsp = hWs + c * Hc;
    const float* wtp = hWt + c * Hc;
    float pb[4] = {0,0,0,0}, ps[4] = {0,0,0,0}, pt[4] = {0,0,0,0};
    #pragma unroll
    for (int nt = 0; nt < 16; ++nt) {
        int col = nt * 16 + l15;
        float bv = b3c[col];
        float wb = wbp[col], wsv = wsp[col], wtv = wtp[col];
        #pragma unroll
        for (int r = 0; r < 4; ++r) {
            float h = sigmoidf_(acc[nt][r] + bv);
            pb[r] += h * wb; ps[r] += h * wsv; pt[r] += h * wtv;
        }
    }
    #pragma unroll
    for (int m = 1; m < 16; m <<= 1) {
        #pragma unroll
        for (int r = 0; r < 4; ++r) {
            pb[r] += __shfl_xor(pb[r], m);
            ps[r] += __shfl_xor(ps[r], m);
            pt[r] += __shfl_xor(pt[r], m);
        }
    }
    if (l15 == 0) {
        float hb1 = hbb[c], hb2 = hbs[c], hb3 = hbt[c];
        #pragma unroll
        for (int r = 0; r < 4; ++r) {
            int g = row0 + wave * 16 + lg * 4 + r;
            if (g < n_c) {
                int R = rowlist[base + g];
                out[R]           = sigmoidf_(pb[r] + hb1);
                out[B_N + R]     = tanhf(ps[r] + hb2);
                out[2 * B_N + R] = sigmoidf_(pt[r] + hb3);
            }
        }
    }
}

extern "C" void kernel_launch(void* const* d_in, const int* in_sizes, int n_in,
                              void* d_out, int out_size, void* d_ws, size_t ws_size,
                              hipStream_t stream)
{
    const float* rgb = (const float*)d_in[0];
    const float* spd = (const float*)d_in[1];
    const int*   cmd = (const int*)d_in[2];
    const float* sW1 = (const float*)d_in[3];
    const float* sb1 = (const float*)d_in[4];
    const float* sW2 = (const float*)d_in[5];
    const float* sb2 = (const float*)d_in[6];
    const float* sW3 = (const float*)d_in[7];
    const float* sb3 = (const float*)d_in[8];
    const float* W1  = (const float*)d_in[9];
    const float* b1  = (const float*)d_in[10];
    const float* W2  = (const float*)d_in[11];
    const float* b2  = (const float*)d_in[12];
    const float* W3  = (const float*)d_in[13];
    const float* b3  = (const float*)d_in[14];
    const float* hWb = (const float*)d_in[15];
    const float* hbb = (const float*)d_in[16];
    const float* hWs = (const float*)d_in[17];
    const float* hbs = (const float*)d_in[18];
    const float* hWt = (const float*)d_in[19];
    const float* hbt = (const float*)d_in[20];

    char* ws = (char*)d_ws;
    size_t off = 0;
    auto take = [&](size_t bytes) { char* p = ws + off; off = (off + bytes + 255) & ~(size_t)255; return p; };
    __bf16* xb   = (__bf16*)take((size_t)B_N * D_INc * 2);        // 41.9 MB
    __bf16* w1t  = (__bf16*)take((size_t)Cc * Hc * D_INc * 2);    // 2.3 MB
    __bf16* w2t  = (__bf16*)take((size_t)Cc * Hc * Hc * 2);       // 0.9 MB
    __bf16* w3t  = (__bf16*)take((size_t)Cc * Hc * Hc * 2);       // 0.9 MB
    int* rowlist = (int*)take((size_t)B_N * 4);                   // 131 KB
    int* hist_part = (int*)take(64 * Cc * 4);
    int* cof     = (int*)take(24 * 4);                            // cnt | offs | fill

    transpose_kernel<<<dim3(8, 20, 21), dim3(32, 8), 0, stream>>>(W1, W2, W3, w1t, w2t, w3t);
    build_x_kernel<<<8192, 128, 0, stream>>>(rgb, spd, sW1, sb1, sW2, sb2, sW3, sb3, xb);
    hist_kernel<<<64, 256, 0, stream>>>(cmd, hist_part);
    scan_kernel<<<1, 64, 0, stream>>>(hist_part, cof);
    scatter_kernel<<<128, 256, 0, stream>>>(cmd, cof, rowlist);
    branch_mlp_kernel<<<dim3(512, Cc), 256, 0, stream>>>(xb, w1t, w2t, w3t,
        b1, b2, b3, hWb, hbb, hWs, hbs, hWt, hbt, cof, rowlist, (float*)d_out);
}

// Round 3
// 335.904 us; speedup vs baseline: 1.6375x; 1.6375x over previous
//
#include <hip/hip_runtime.h>

#define B_N   32768
#define D_RGBc 512
#define D_SPDc 128
#define D_INc  640
#define Hc     256
#define Cc     7

typedef __bf16 bf16x8 __attribute__((ext_vector_type(8)));
typedef float  f32x4  __attribute__((ext_vector_type(4)));
typedef float  f32x16 __attribute__((ext_vector_type(16)));

__device__ __forceinline__ float sigmoidf_(float x) { return 1.0f / (1.0f + __expf(-x)); }

// ---------- weights -> bf16, transposed to [n][k] ----------
__global__ void transpose_kernel(const float* __restrict__ W1, const float* __restrict__ W2,
                                 const float* __restrict__ W3,
                                 const float* __restrict__ sW2, const float* __restrict__ sW3,
                                 __bf16* __restrict__ w1t, __bf16* __restrict__ w2t,
                                 __bf16* __restrict__ w3t,
                                 __bf16* __restrict__ sw2t, __bf16* __restrict__ sw3t)
{
    int m = blockIdx.z;   // 0..6 W1, 7..13 W2, 14..20 W3, 21 sW2, 22 sW3
    const float* src; __bf16* dst; int K, N;
    if (m < 7)       { src = W1 + (size_t)m * D_INc * Hc;      dst = w1t + (size_t)m * Hc * D_INc; K = D_INc; N = Hc; }
    else if (m < 14) { int c = m - 7;  src = W2 + (size_t)c * Hc * Hc; dst = w2t + (size_t)c * Hc * Hc; K = Hc; N = Hc; }
    else if (m < 21) { int c = m - 14; src = W3 + (size_t)c * Hc * Hc; dst = w3t + (size_t)c * Hc * Hc; K = Hc; N = Hc; }
    else if (m == 21){ src = sW2; dst = sw2t; K = D_SPDc; N = D_SPDc; }
    else             { src = sW3; dst = sw3t; K = D_SPDc; N = D_SPDc; }
    int k0 = blockIdx.y * 32, n0 = blockIdx.x * 32;
    if (k0 >= K || n0 >= N) return;
    __shared__ float tile[32][33];
    int tx = threadIdx.x, ty = threadIdx.y;     // 32 x 8
    #pragma unroll
    for (int i = 0; i < 32; i += 8)
        tile[ty + i][tx] = src[(size_t)(k0 + ty + i) * N + n0 + tx];
    __syncthreads();
    #pragma unroll
    for (int i = 0; i < 32; i += 8)
        dst[(size_t)(n0 + ty + i) * K + k0 + tx] = (__bf16)tile[tx][ty + i];
}

// ---------- bucket rows by cmd ----------
__global__ void hist_kernel(const int* __restrict__ cmd, int* __restrict__ hist_part)
{
    __shared__ int h[Cc];
    if (threadIdx.x < Cc) h[threadIdx.x] = 0;
    __syncthreads();
    for (int i = blockIdx.x * 256 + threadIdx.x; i < B_N; i += 64 * 256)
        atomicAdd(&h[cmd[i]], 1);
    __syncthreads();
    if (threadIdx.x < Cc) hist_part[blockIdx.x * Cc + threadIdx.x] = h[threadIdx.x];
}

__global__ void scan_kernel(const int* __restrict__ hist_part, int* __restrict__ cof)
{
    int l = threadIdx.x;                       // 64
    int v[Cc];
    #pragma unroll
    for (int c = 0; c < Cc; ++c) v[c] = hist_part[l * Cc + c];
    #pragma unroll
    for (int c = 0; c < Cc; ++c)
        for (int m = 1; m < 64; m <<= 1) v[c] += __shfl_xor(v[c], m);
    if (l == 0) {
        int run = 0;
        for (int c = 0; c < Cc; ++c) {
            cof[c] = v[c]; cof[8 + c] = run; cof[16 + c] = run; run += v[c];
        }
    }
}

__global__ void scatter_kernel(const int* __restrict__ cmd, int* __restrict__ cof,
                               int* __restrict__ rowlist)
{
    int i = blockIdx.x * 256 + threadIdx.x;
    int lane = threadIdx.x & 63;
    int cv = cmd[i];
    #pragma unroll
    for (int c = 0; c < Cc; ++c) {
        unsigned long long mask = __ballot(cv == c);
        if (mask == 0ull) continue;
        int leader = __ffsll((unsigned long long)mask) - 1;
        int basep = 0;
        if (lane == leader) basep = atomicAdd(&cof[16 + c], (int)__popcll(mask));
        basep = __shfl(basep, leader);
        if (cv == c) {
            int rank = (int)__popcll(mask & ((1ull << lane) - 1ull));
            rowlist[basep + rank] = i;
        }
    }
}

// ---------- MFMA helpers (32x32x16; C/D: col=lane&31, row=(reg&3)+8*(reg>>2)+4*(lane>>5)) ----------
__device__ __forceinline__ void zeroacc(f32x16* a, int n)
{
    for (int i = 0; i < n; ++i)
        #pragma unroll
        for (int j = 0; j < 16; ++j) a[i][j] = 0.f;
}

template<int KK, int NT, int ASTR>
__device__ __forceinline__ void layer_lds(const char* aIn, const __bf16* wt, int kOff, int wK,
                                          int colBase, int l31, int hi, f32x16* acc)
{
    #pragma unroll 4
    for (int ks = 0; ks < KK / 16; ++ks) {
        bf16x8 a = *(const bf16x8*)(aIn + l31 * ASTR + (((ks * 16 + hi * 8) * 2) ^ ((l31 & 15) << 4)));
        #pragma unroll
        for (int nt = 0; nt < NT; ++nt) {
            bf16x8 b = *(const bf16x8*)(wt + (size_t)(colBase + nt * 32 + l31) * wK + kOff + ks * 16 + hi * 8);
            acc[nt] = __builtin_amdgcn_mfma_f32_32x32x16_bf16(a, b, acc[nt], 0, 0, 0);
        }
    }
}

template<int NT, bool TANH, int STRIDE>
__device__ __forceinline__ void store_act(char* dst, const float* bias, int colBase,
                                          int l31, int hi, const f32x16* acc)
{
    #pragma unroll
    for (int nt = 0; nt < NT; ++nt) {
        int col = colBase + nt * 32 + l31;
        float bv = bias[col];
        #pragma unroll
        for (int rg = 0; rg < 16; ++rg) {
            int row = (rg & 3) + 8 * (rg >> 2) + 4 * hi;
            float v = acc[nt][rg] + bv;
            v = TANH ? tanhf(v) : sigmoidf_(v);
            *(__bf16*)(dst + row * STRIDE + ((col * 2) ^ ((row & 15) << 4))) = (__bf16)v;
        }
    }
}

// ---------- main fused kernel: 32 rows/block, 2 waves (N-split 128 cols each) ----------
__launch_bounds__(128, 2)
__global__ void branch_mlp_kernel(
    const float* __restrict__ rgb, const float* __restrict__ spd,
    const float* __restrict__ sW1, const float* __restrict__ sb1,
    const float* __restrict__ sb2, const float* __restrict__ sb3,
    const __bf16* __restrict__ sw2t, const __bf16* __restrict__ sw3t,
    const __bf16* __restrict__ w1t, const __bf16* __restrict__ w2t, const __bf16* __restrict__ w3t,
    const float* __restrict__ b1, const float* __restrict__ b2, const float* __restrict__ b3,
    const float* __restrict__ hWb, const float* __restrict__ hbb,
    const float* __restrict__ hWs, const float* __restrict__ hbs,
    const float* __restrict__ hWt, const float* __restrict__ hbt,
    const int* __restrict__ cof, const int* __restrict__ rowlist,
    float* __restrict__ out)
{
    __shared__ char actA[32 * 512];      // 16 KB, XOR-swizzled
    __shared__ char actB[32 * 512];      // 16 KB
    __shared__ char s3b[32 * 256];       // 8 KB  (speed features, 128 cols)
    __shared__ float headbuf[2][32][3];

    // flat block id -> (branch c, 32-row group g)
    int bid = blockIdx.x;
    int c = -1, g = 0, accg = 0;
    #pragma unroll
    for (int i = 0; i < Cc; ++i) {
        int gc = (cof[i] + 31) >> 5;
        if (c < 0 && bid < accg + gc) { c = i; g = bid - accg; }
        accg += gc;
    }
    if (c < 0) return;
    int n_c = cof[c], base = cof[8 + c];

    int tid = threadIdx.x, wave = tid >> 6, lane = tid & 63, l31 = lane & 31, hi = lane >> 5;
    int colB = wave * 128;               // this wave's 128-col half

    int gr = g * 32 + l31;
    int myrow = rowlist[base + (gr < n_c ? gr : 0)];   // clamped dup for tail

    // phase 0: s1 = tanh(spd*W1+b1) -> actA[32][128]
    {
        int r = tid >> 2, jb = (tid & 3) * 32;
        int gg = g * 32 + r;
        float sv = spd[rowlist[base + (gg < n_c ? gg : 0)]];
        #pragma unroll
        for (int jj = 0; jj < 32; ++jj) {
            int j = jb + jj;
            float v = tanhf(sv * sW1[j] + sb1[j]);
            *(__bf16*)(actA + r * 512 + ((j * 2) ^ ((r & 15) << 4))) = (__bf16)v;
        }
    }
    __syncthreads();

    // phase 1: s2 = tanh(s1 @ sW2) -> actB   (each wave: 64 cols)
    f32x16 sacc[2];
    zeroacc(sacc, 2);
    layer_lds<128, 2, 512>(actA, sw2t, 0, D_SPDc, wave * 64, l31, hi, sacc);
    store_act<2, true, 512>(actB, sb2, wave * 64, l31, hi, sacc);
    __syncthreads();

    // phase 2: s3 = tanh(s2 @ sW3) -> s3b
    zeroacc(sacc, 2);
    layer_lds<128, 2, 512>(actB, sw3t, 0, D_SPDc, wave * 64, l31, hi, sacc);
    store_act<2, true, 256>(s3b, sb3, wave * 64, l31, hi, sacc);
    __syncthreads();

    // phase 3: layer 1  (K=640: 512 from rgb f32, 128 from s3b) -> actA
    f32x16 acc[4];
    zeroacc(acc, 4);
    {
        const float* rgbrow = rgb + (size_t)myrow * D_RGBc + hi * 8;
        const __bf16* w1c = w1t + (size_t)c * Hc * D_INc;
        #pragma unroll 4
        for (int ks = 0; ks < 32; ++ks) {
            f32x4 a0 = *(const f32x4*)(rgbrow + ks * 16);
            f32x4 a1 = *(const f32x4*)(rgbrow + ks * 16 + 4);
            bf16x8 a;
            #pragma unroll
            for (int j = 0; j < 4; ++j) { a[j] = (__bf16)a0[j]; a[4 + j] = (__bf16)a1[j]; }
            #pragma unroll
            for (int nt = 0; nt < 4; ++nt) {
                bf16x8 b = *(const bf16x8*)(w1c + (size_t)(colB + nt * 32 + l31) * D_INc + ks * 16 + hi * 8);
                acc[nt] = __builtin_amdgcn_mfma_f32_32x32x16_bf16(a, b, acc[nt], 0, 0, 0);
            }
        }
        layer_lds<128, 4, 256>(s3b, w1c, 512, D_INc, colB, l31, hi, acc);
    }
    store_act<4, false, 512>(actA, b1 + c * Hc, colB, l31, hi, acc);
    __syncthreads();

    // phase 4: layer 2 -> actB
    zeroacc(acc, 4);
    layer_lds<256, 4, 512>(actA, w2t + (size_t)c * Hc * Hc, 0, Hc, colB, l31, hi, acc);
    store_act<4, false, 512>(actB, b2 + c * Hc, colB, l31, hi, acc);
    __syncthreads();

    // phase 5: layer 3 (stay in registers) + heads
    zeroacc(acc, 4);
    layer_lds<256, 4, 512>(actB, w3t + (size_t)c * Hc * Hc, 0, Hc, colB, l31, hi, acc);

    const float* b3c = b3 + c * Hc;
    float wgt[3][4];
    #pragma unroll
    for (int nt = 0; nt < 4; ++nt) {
        int col = colB + nt * 32 + l31;
        wgt[0][nt] = hWb[c * Hc + col];
        wgt[1][nt] = hWs[c * Hc + col];
        wgt[2][nt] = hWt[c * Hc + col];
    }
    float pr[3][16];
    #pragma unroll
    for (int hd = 0; hd < 3; ++hd)
        #pragma unroll
        for (int rg = 0; rg < 16; ++rg) pr[hd][rg] = 0.f;
    #pragma unroll
    for (int nt = 0; nt < 4; ++nt) {
        int col = colB + nt * 32 + l31;
        float bv = b3c[col];
        #pragma unroll
        for (int rg = 0; rg < 16; ++rg) {
            float h = sigmoidf_(acc[nt][rg] + bv);
            pr[0][rg] += h * wgt[0][nt];
            pr[1][rg] += h * wgt[1][nt];
            pr[2][rg] += h * wgt[2][nt];
        }
    }
    #pragma unroll
    for (int m = 1; m < 32; m <<= 1)
        #pragma unroll
        for (int hd = 0; hd < 3; ++hd)
            #pragma unroll
            for (int rg = 0; rg < 16; ++rg)
                pr[hd][rg] += __shfl_xor(pr[hd][rg], m);
    if (l31 == 0) {
        #pragma unroll
        for (int rg = 0; rg < 16; ++rg) {
            int row = (rg & 3) + 8 * (rg >> 2) + 4 * hi;
            headbuf[wave][row][0] = pr[0][rg];
            headbuf[wave][row][1] = pr[1][rg];
            headbuf[wave][row][2] = pr[2][rg];
        }
    }
    __syncthreads();
    if (tid < 96) {
        int row = tid / 3, hd = tid % 3;
        int gg = g * 32 + row;
        if (gg < n_c) {
            int R = rowlist[base + gg];
            float v = headbuf[0][row][hd] + headbuf[1][row][hd];
            if (hd == 0)      out[R]           = sigmoidf_(v + hbb[c]);
            else if (hd == 1) out[B_N + R]     = tanhf(v + hbs[c]);
            else              out[2 * B_N + R] = sigmoidf_(v + hbt[c]);
        }
    }
}

extern "C" void kernel_launch(void* const* d_in, const int* in_sizes, int n_in,
                              void* d_out, int out_size, void* d_ws, size_t ws_size,
                              hipStream_t stream)
{
    const float* rgb = (const float*)d_in[0];
    const float* spd = (const float*)d_in[1];
    const int*   cmd = (const int*)d_in[2];
    const float* sW1 = (const float*)d_in[3];
    const float* sb1 = (const float*)d_in[4];
    const float* sW2 = (const float*)d_in[5];
    const float* sb2 = (const float*)d_in[6];
    const float* sW3 = (const float*)d_in[7];
    const float* sb3 = (const float*)d_in[8];
    const float* W1  = (const float*)d_in[9];
    const float* b1  = (const float*)d_in[10];
    const float* W2  = (const float*)d_in[11];
    const float* b2  = (const float*)d_in[12];
    const float* W3  = (const float*)d_in[13];
    const float* b3  = (const float*)d_in[14];
    const float* hWb = (const float*)d_in[15];
    const float* hbb = (const float*)d_in[16];
    const float* hWs = (const float*)d_in[17];
    const float* hbs = (const float*)d_in[18];
    const float* hWt = (const float*)d_in[19];
    const float* hbt = (const float*)d_in[20];

    char* ws = (char*)d_ws;
    size_t off = 0;
    auto take = [&](size_t bytes) { char* p = ws + off; off = (off + bytes + 255) & ~(size_t)255; return p; };
    __bf16* w1t  = (__bf16*)take((size_t)Cc * Hc * D_INc * 2);
    __bf16* w2t  = (__bf16*)take((size_t)Cc * Hc * Hc * 2);
    __bf16* w3t  = (__bf16*)take((size_t)Cc * Hc * Hc * 2);
    __bf16* sw2t = (__bf16*)take((size_t)D_SPDc * D_SPDc * 2);
    __bf16* sw3t = (__bf16*)take((size_t)D_SPDc * D_SPDc * 2);
    int* rowlist = (int*)take((size_t)B_N * 4);
    int* hist_part = (int*)take(64 * Cc * 4);
    int* cof     = (int*)take(24 * 4);

    transpose_kernel<<<dim3(8, 20, 23), dim3(32, 8), 0, stream>>>(W1, W2, W3, sW2, sW3,
                                                                  w1t, w2t, w3t, sw2t, sw3t);
    hist_kernel<<<64, 256, 0, stream>>>(cmd, hist_part);
    scan_kernel<<<1, 64, 0, stream>>>(hist_part, cof);
    scatter_kernel<<<128, 256, 0, stream>>>(cmd, cof, rowlist);
    branch_mlp_kernel<<<dim3(1031), 128, 0, stream>>>(rgb, spd, sW1, sb1, sb2, sb3,
        sw2t, sw3t, w1t, w2t, w3t, b1, b2, b3,
        hWb, hbb, hWs, hbs, hWt, hbt, cof, rowlist, (float*)d_out);
}

// Round 5
// 301.626 us; speedup vs baseline: 1.8236x; 1.1136x over previous
//
#include <hip/hip_runtime.h>

#define B_N   32768
#define D_RGBc 512
#define D_SPDc 128
#define D_INc  640
#define Hc     256
#define Cc     7

typedef __bf16 bf16x8 __attribute__((ext_vector_type(8)));
typedef float  f32x4  __attribute__((ext_vector_type(4)));
typedef float  f32x16 __attribute__((ext_vector_type(16)));
typedef unsigned int u32;

__device__ __forceinline__ float sigmoidf_(float x) { return 1.0f / (1.0f + __expf(-x)); }

// LDS swizzles: XOR row-dependent 16B slot into the byte offset (bits >=4 only,
// so 16B-aligned chunks stay contiguous and 2B writes stay consistent).
__device__ __forceinline__ u32 aswz(int row, int kbyte) { return (u32)(row * 512 + (kbyte ^ ((row & 31) << 4))); }
__device__ __forceinline__ u32 sswz(int row, int kbyte) { return (u32)(row * 256 + (kbyte ^ ((row & 15) << 4))); }

// ---------------- pack weights into MFMA B-fragment order ----------------
// packed[m]: frag index f = (ntile*(K/16) + ks)*64 + lane; 16B at f*16.
// frag(lane) = W[k0 + ks*16 + (lane>>5)*8 + j][ntile*32 + (lane&31)], j=0..7
__global__ void pack_kernel(const float* __restrict__ W1, const float* __restrict__ W2,
                            const float* __restrict__ W3, const float* __restrict__ sW2,
                            const float* __restrict__ sW3,
                            __bf16* __restrict__ p1, __bf16* __restrict__ p2,
                            __bf16* __restrict__ p3, __bf16* __restrict__ ps2,
                            __bf16* __restrict__ ps3)
{
    int bid = blockIdx.x;
    const float* src; __bf16* dst; int K, N, nt, kc;
    if (bid < 560)      { int c = bid / 80, r = bid % 80; nt = r / 10; kc = r % 10;
        src = W1 + (size_t)c * D_INc * Hc; dst = p1 + (size_t)c * Hc * D_INc; K = D_INc; N = Hc; }
    else if (bid < 784) { int b = bid - 560; int c = b / 32, r = b % 32; nt = r / 4; kc = r % 4;
        src = W2 + (size_t)c * Hc * Hc; dst = p2 + (size_t)c * Hc * Hc; K = Hc; N = Hc; }
    else if (bid < 1008){ int b = bid - 784; int c = b / 32, r = b % 32; nt = r / 4; kc = r % 4;
        src = W3 + (size_t)c * Hc * Hc; dst = p3 + (size_t)c * Hc * Hc; K = Hc; N = Hc; }
    else if (bid < 1016){ int r = bid - 1008; nt = r / 2; kc = r % 2; src = sW2; dst = ps2; K = D_SPDc; N = D_SPDc; }
    else                { int r = bid - 1016; nt = r / 2; kc = r % 2; src = sW3; dst = ps3; K = D_SPDc; N = D_SPDc; }
    int k0 = kc * 64, n0 = nt * 32;
    __shared__ float tile[64][33];
    int t = threadIdx.x;
    int col = t & 31, r8 = (t >> 5) * 8;
    #pragma unroll
    for (int i = 0; i < 8; ++i)
        tile[r8 + i][col] = src[(size_t)(k0 + r8 + i) * N + n0 + col];
    __syncthreads();
    int ksl = t >> 6, lane = t & 63, l31 = lane & 31, hi = lane >> 5;
    bf16x8 v;
    #pragma unroll
    for (int j = 0; j < 8; ++j) v[j] = (__bf16)tile[ksl * 16 + hi * 8 + j][l31];
    *(bf16x8*)(dst + ((size_t)(nt * (K / 16) + (k0 >> 4) + ksl) * 64 + lane) * 8) = v;
}

// ---------------- hist + scan + scatter fused (single block) ----------------
__launch_bounds__(1024)
__global__ void prep_kernel(const int* __restrict__ cmd, int* __restrict__ cof,
                            int* __restrict__ rowlist)
{
    __shared__ int h[8], fill[8];
    int t = threadIdx.x, lane = t & 63;
    if (t < 8) h[t] = 0;
    __syncthreads();
    for (int i = t; i < B_N; i += 1024) {
        int cv = cmd[i];
        #pragma unroll
        for (int c = 0; c < Cc; ++c) {
            unsigned long long m = __ballot(cv == c);
            if (!m) continue;
            int leader = __ffsll(m) - 1;
            if (lane == leader) atomicAdd(&h[c], (int)__popcll(m));
        }
    }
    __syncthreads();
    if (t == 0) {
        int run = 0;
        for (int c = 0; c < Cc; ++c) { int v = h[c]; cof[c] = v; cof[8 + c] = run; fill[c] = run; run += v; }
    }
    __syncthreads();
    for (int i = t; i < B_N; i += 1024) {
        int cv = cmd[i];
        #pragma unroll
        for (int c = 0; c < Cc; ++c) {
            unsigned long long m = __ballot(cv == c);
            if (!m) continue;
            int leader = __ffsll(m) - 1;
            int basep = 0;
            if (lane == leader) basep = atomicAdd(&fill[c], (int)__popcll(m));
            basep = __shfl(basep, leader);
            if (cv == c) {
                int rank = (int)__popcll(m & ((1ull << lane) - 1ull));
                rowlist[basep + rank] = i;
            }
        }
    }
}

// ---------------- main fused kernel: 32 rows/block, 4 waves (64 cols each) ----------------
__launch_bounds__(256, 4)
__global__ void branch_mlp_kernel(
    const float* __restrict__ rgb, const float* __restrict__ spd,
    const float* __restrict__ sW1, const float* __restrict__ sb1,
    const float* __restrict__ sb2, const float* __restrict__ sb3,
    const __bf16* __restrict__ ps2, const __bf16* __restrict__ ps3,
    const __bf16* __restrict__ p1, const __bf16* __restrict__ p2, const __bf16* __restrict__ p3,
    const float* __restrict__ b1, const float* __restrict__ b2, const float* __restrict__ b3,
    const float* __restrict__ hWb, const float* __restrict__ hbb,
    const float* __restrict__ hWs, const float* __restrict__ hbs,
    const float* __restrict__ hWt, const float* __restrict__ hbt,
    const int* __restrict__ cof, const int* __restrict__ rowlist,
    float* __restrict__ out)
{
    __shared__ char act[32 * 512];     // 16 KB: 32 rows x 256 cols bf16 (swizzled)
    __shared__ char sbuf[32 * 256];    // 8 KB: speed acts s1/s2/s3 (generations)
    __shared__ float headbuf[4][32][3];

    // flat block id -> (branch c, 32-row group g)
    int bid = blockIdx.x;
    int c = -1, g = 0, accg = 0;
    #pragma unroll
    for (int i = 0; i < Cc; ++i) {
        int gc = (cof[i] + 31) >> 5;
        if (c < 0 && bid < accg + gc) { c = i; g = bid - accg; }
        accg += gc;
    }
    if (c < 0) return;
    int n_c = cof[c], base = cof[8 + c];

    int tid = threadIdx.x, wave = tid >> 6, lane = tid & 63, l31 = lane & 31, hi = lane >> 5;

    int grow = g * 32 + l31;
    int rid = rowlist[base + (grow < n_c ? grow : n_c - 1)];   // clamped dup for tail

    // phase 0: s1 = tanh(spd*sW1 + sb1) -> sbuf[32][128]
    {
        int row = tid >> 3, j0 = (tid & 7) * 16;
        int gg = g * 32 + row;
        float sv = spd[rowlist[base + (gg < n_c ? gg : n_c - 1)]];
        #pragma unroll
        for (int jj = 0; jj < 16; ++jj) {
            int j = j0 + jj;
            float v = tanhf(sv * sW1[j] + sb1[j]);
            *(__bf16*)(sbuf + sswz(row, j * 2)) = (__bf16)v;
        }
    }
    __syncthreads();

    f32x16 acc0, acc1;

    // phase 1: s2 = tanh(s1 @ sW2), wave computes cols wave*32..+31 (K=128)
    #pragma unroll
    for (int j = 0; j < 16; ++j) acc0[j] = 0.f;
    {
        const __bf16* pw = ps2 + ((size_t)(wave * 8) * 64 + lane) * 8;
        #pragma unroll
        for (int ks = 0; ks < 8; ++ks) {
            bf16x8 a = *(const bf16x8*)(sbuf + sswz(l31, (ks * 16 + hi * 8) * 2));
            bf16x8 b = *(const bf16x8*)(pw + (size_t)ks * 512);
            acc0 = __builtin_amdgcn_mfma_f32_32x32x16_bf16(a, b, acc0, 0, 0, 0);
        }
    }
    __syncthreads();                       // all s1 reads done
    {
        int col = wave * 32 + l31;
        float bv = sb2[col];
        #pragma unroll
        for (int rg = 0; rg < 16; ++rg) {
            int row = (rg & 3) + 8 * (rg >> 2) + 4 * hi;
            *(__bf16*)(sbuf + sswz(row, col * 2)) = (__bf16)tanhf(acc0[rg] + bv);
        }
    }
    __syncthreads();

    // phase 2: s3 = tanh(s2 @ sW3)
    #pragma unroll
    for (int j = 0; j < 16; ++j) acc0[j] = 0.f;
    {
        const __bf16* pw = ps3 + ((size_t)(wave * 8) * 64 + lane) * 8;
        #pragma unroll
        for (int ks = 0; ks < 8; ++ks) {
            bf16x8 a = *(const bf16x8*)(sbuf + sswz(l31, (ks * 16 + hi * 8) * 2));
            bf16x8 b = *(const bf16x8*)(pw + (size_t)ks * 512);
            acc0 = __builtin_amdgcn_mfma_f32_32x32x16_bf16(a, b, acc0, 0, 0, 0);
        }
    }
    __syncthreads();
    {
        int col = wave * 32 + l31;
        float bv = sb3[col];
        #pragma unroll
        for (int rg = 0; rg < 16; ++rg) {
            int row = (rg & 3) + 8 * (rg >> 2) + 4 * hi;
            *(__bf16*)(sbuf + sswz(row, col * 2)) = (__bf16)tanhf(acc0[rg] + bv);
        }
    }
    __syncthreads();

    // phase 3: layer1, K=640 (512 rgb f32 + 128 s3), wave cols = tiles 2w, 2w+1
    #pragma unroll
    for (int j = 0; j < 16; ++j) { acc0[j] = 0.f; acc1[j] = 0.f; }
    {
        const float* rr = rgb + (size_t)rid * D_RGBc;
        const __bf16* pw = p1 + (size_t)c * Hc * D_INc;
        const __bf16* pw0 = pw + ((size_t)((2 * wave) * 40) * 64 + lane) * 8;
        const __bf16* pw1 = pw + ((size_t)((2 * wave + 1) * 40) * 64 + lane) * 8;
        #pragma unroll 4
        for (int ks = 0; ks < 32; ++ks) {
            f32x4 x0 = *(const f32x4*)(rr + ks * 16 + hi * 8);
            f32x4 x1 = *(const f32x4*)(rr + ks * 16 + hi * 8 + 4);
            bf16x8 a;
            #pragma unroll
            for (int j = 0; j < 4; ++j) { a[j] = (__bf16)x0[j]; a[4 + j] = (__bf16)x1[j]; }
            bf16x8 b0 = *(const bf16x8*)(pw0 + (size_t)ks * 512);
            bf16x8 b1 = *(const bf16x8*)(pw1 + (size_t)ks * 512);
            acc0 = __builtin_amdgcn_mfma_f32_32x32x16_bf16(a, b0, acc0, 0, 0, 0);
            acc1 = __builtin_amdgcn_mfma_f32_32x32x16_bf16(a, b1, acc1, 0, 0, 0);
        }
        #pragma unroll
        for (int ks = 32; ks < 40; ++ks) {
            bf16x8 a = *(const bf16x8*)(sbuf + sswz(l31, ((ks - 32) * 16 + hi * 8) * 2));
            bf16x8 b0 = *(const bf16x8*)(pw0 + (size_t)ks * 512);
            bf16x8 b1 = *(const bf16x8*)(pw1 + (size_t)ks * 512);
            acc0 = __builtin_amdgcn_mfma_f32_32x32x16_bf16(a, b0, acc0, 0, 0, 0);
            acc1 = __builtin_amdgcn_mfma_f32_32x32x16_bf16(a, b1, acc1, 0, 0, 0);
        }
    }
    // no barrier needed: act not yet read by anyone
    {
        const float* bb = b1 + c * Hc;
        #pragma unroll
        for (int nt = 0; nt < 2; ++nt) {
            int col = wave * 64 + nt * 32 + l31;
            float bv = bb[col];
            const f32x16& a = nt ? acc1 : acc0;
            #pragma unroll
            for (int rg = 0; rg < 16; ++rg) {
                int row = (rg & 3) + 8 * (rg >> 2) + 4 * hi;
                *(__bf16*)(act + aswz(row, col * 2)) = (__bf16)sigmoidf_(a[rg] + bv);
            }
        }
    }
    __syncthreads();

    // phase 4: layer2, K=256
    #pragma unroll
    for (int j = 0; j < 16; ++j) { acc0[j] = 0.f; acc1[j] = 0.f; }
    {
        const __bf16* pw = p2 + (size_t)c * Hc * Hc;
        const __bf16* pw0 = pw + ((size_t)((2 * wave) * 16) * 64 + lane) * 8;
        const __bf16* pw1 = pw + ((size_t)((2 * wave + 1) * 16) * 64 + lane) * 8;
        #pragma unroll 4
        for (int ks = 0; ks < 16; ++ks) {
            bf16x8 a = *(const bf16x8*)(act + aswz(l31, (ks * 16 + hi * 8) * 2));
            bf16x8 b0 = *(const bf16x8*)(pw0 + (size_t)ks * 512);
            bf16x8 b1 = *(const bf16x8*)(pw1 + (size_t)ks * 512);
            acc0 = __builtin_amdgcn_mfma_f32_32x32x16_bf16(a, b0, acc0, 0, 0, 0);
            acc1 = __builtin_amdgcn_mfma_f32_32x32x16_bf16(a, b1, acc1, 0, 0, 0);
        }
    }
    __syncthreads();                       // all layer-2 reads of act done
    {
        const float* bb = b2 + c * Hc;
        #pragma unroll
        for (int nt = 0; nt < 2; ++nt) {
            int col = wave * 64 + nt * 32 + l31;
            float bv = bb[col];
            const f32x16& a = nt ? acc1 : acc0;
            #pragma unroll
            for (int rg = 0; rg < 16; ++rg) {
                int row = (rg & 3) + 8 * (rg >> 2) + 4 * hi;
                *(__bf16*)(act + aswz(row, col * 2)) = (__bf16)sigmoidf_(a[rg] + bv);
            }
        }
    }
    __syncthreads();

    // phase 5: layer3 (acc stays in regs) + heads
    #pragma unroll
    for (int j = 0; j < 16; ++j) { acc0[j] = 0.f; acc1[j] = 0.f; }
    {
        const __bf16* pw = p3 + (size_t)c * Hc * Hc;
        const __bf16* pw0 = pw + ((size_t)((2 * wave) * 16) * 64 + lane) * 8;
        const __bf16* pw1 = pw + ((size_t)((2 * wave + 1) * 16) * 64 + lane) * 8;
        #pragma unroll 4
        for (int ks = 0; ks < 16; ++ks) {
            bf16x8 a = *(const bf16x8*)(act + aswz(l31, (ks * 16 + hi * 8) * 2));
            bf16x8 b0 = *(const bf16x8*)(pw0 + (size_t)ks * 512);
            bf16x8 b1 = *(const bf16x8*)(pw1 + (size_t)ks * 512);
            acc0 = __builtin_amdgcn_mfma_f32_32x32x16_bf16(a, b0, acc0, 0, 0, 0);
            acc1 = __builtin_amdgcn_mfma_f32_32x32x16_bf16(a, b1, acc1, 0, 0, 0);
        }
    }

    float pr[3][16];
    #pragma unroll
    for (int hd = 0; hd < 3; ++hd)
        #pragma unroll
        for (int rg = 0; rg < 16; ++rg) pr[hd][rg] = 0.f;
    {
        const float* b3c = b3 + c * Hc;
        #pragma unroll
        for (int nt = 0; nt < 2; ++nt) {
            int col = wave * 64 + nt * 32 + l31;
            float bv = b3c[col];
            float wb = hWb[c * Hc + col], wsv = hWs[c * Hc + col], wtv = hWt[c * Hc + col];
            const f32x16& a = nt ? acc1 : acc0;
            #pragma unroll
            for (int rg = 0; rg < 16; ++rg) {
                float h = sigmoidf_(a[rg] + bv);
                pr[0][rg] += h * wb;
                pr[1][rg] += h * wsv;
                pr[2][rg] += h * wtv;
            }
        }
    }
    #pragma unroll
    for (int m = 1; m < 32; m <<= 1)
        #pragma unroll
        for (int hd = 0; hd < 3; ++hd)
            #pragma unroll
            for (int rg = 0; rg < 16; ++rg)
                pr[hd][rg] += __shfl_xor(pr[hd][rg], m);   // reduce over l31 (stays in 32-half)
    if (l31 == 0) {
        #pragma unroll
        for (int rg = 0; rg < 16; ++rg) {
            int row = (rg & 3) + 8 * (rg >> 2) + 4 * hi;
            headbuf[wave][row][0] = pr[0][rg];
            headbuf[wave][row][1] = pr[1][rg];
            headbuf[wave][row][2] = pr[2][rg];
        }
    }
    __syncthreads();
    if (tid < 96) {
        int row = tid / 3, hd = tid % 3;
        int gg = g * 32 + row;
        if (gg < n_c) {
            int R = rowlist[base + gg];
            float v = headbuf[0][row][hd] + headbuf[1][row][hd] + headbuf[2][row][hd] + headbuf[3][row][hd];
            if (hd == 0)      out[R]           = sigmoidf_(v + hbb[c]);
            else if (hd == 1) out[B_N + R]     = tanhf(v + hbs[c]);
            else              out[2 * B_N + R] = sigmoidf_(v + hbt[c]);
        }
    }
}

extern "C" void kernel_launch(void* const* d_in, const int* in_sizes, int n_in,
                              void* d_out, int out_size, void* d_ws, size_t ws_size,
                              hipStream_t stream)
{
    const float* rgb = (const float*)d_in[0];
    const float* spd = (const float*)d_in[1];
    const int*   cmd = (const int*)d_in[2];
    const float* sW1 = (const float*)d_in[3];
    const float* sb1 = (const float*)d_in[4];
    const float* sW2 = (const float*)d_in[5];
    const float* sb2 = (const float*)d_in[6];
    const float* sW3 = (const float*)d_in[7];
    const float* sb3 = (const float*)d_in[8];
    const float* W1  = (const float*)d_in[9];
    const float* b1  = (const float*)d_in[10];
    const float* W2  = (const float*)d_in[11];
    const float* b2  = (const float*)d_in[12];
    const float* W3  = (const float*)d_in[13];
    const float* b3  = (const float*)d_in[14];
    const float* hWb = (const float*)d_in[15];
    const float* hbb = (const float*)d_in[16];
    const float* hWs = (const float*)d_in[17];
    const float* hbs = (const float*)d_in[18];
    const float* hWt = (const float*)d_in[19];
    const float* hbt = (const float*)d_in[20];

    char* ws = (char*)d_ws;
    size_t off = 0;
    auto take = [&](size_t bytes) { char* p = ws + off; off = (off + bytes + 255) & ~(size_t)255; return p; };
    __bf16* p1  = (__bf16*)take((size_t)Cc * Hc * D_INc * 2);
    __bf16* p2  = (__bf16*)take((size_t)Cc * Hc * Hc * 2);
    __bf16* p3  = (__bf16*)take((size_t)Cc * Hc * Hc * 2);
    __bf16* ps2 = (__bf16*)take((size_t)D_SPDc * D_SPDc * 2);
    __bf16* ps3 = (__bf16*)take((size_t)D_SPDc * D_SPDc * 2);
    int* rowlist = (int*)take((size_t)B_N * 4);
    int* cof     = (int*)take(24 * 4);

    pack_kernel<<<1024, 256, 0, stream>>>(W1, W2, W3, sW2, sW3, p1, p2, p3, ps2, ps3);
    prep_kernel<<<1, 1024, 0, stream>>>(cmd, cof, rowlist);
    branch_mlp_kernel<<<1031, 256, 0, stream>>>(rgb, spd, sW1, sb1, sb2, sb3,
        ps2, ps3, p1, p2, p3, b1, b2, b3,
        hWb, hbb, hWs, hbs, hWt, hbt, cof, rowlist, (float*)d_out);
}

// Round 6
// 231.766 us; speedup vs baseline: 2.3733x; 1.3014x over previous
//
#include <hip/hip_runtime.h>

#define B_N   32768
#define D_RGBc 512
#define D_SPDc 128
#define D_INc  640
#define Hc     256
#define Cc     7

typedef __bf16 bf16x8 __attribute__((ext_vector_type(8)));
typedef float  f32x4  __attribute__((ext_vector_type(4)));
typedef float  f32x16 __attribute__((ext_vector_type(16)));
typedef unsigned int u32;

__device__ __forceinline__ float sigmoidf_(float x) { return 1.0f / (1.0f + __expf(-x)); }
__device__ __forceinline__ float tanhf_(float x)    { float e = __expf(2.f * x); return (e - 1.f) / (e + 1.f); }

// Chunked-XOR LDS layout: 128-col bf16 chunks, row stride 256 B inside a chunk.
// XOR bits 4-7 with row -> a fixed col spreads 16 rows over 16 distinct 16B slots
// (~2-way conflict on b128 reads = free). 16B-granule safe, 2B-write safe.
__device__ __forceinline__ u32 xoff(int row, int col) {   // col in elements
    return (u32)(((col >> 7) << 13) + (row << 8) + ((((col & 127) << 1)) ^ ((row & 15) << 4)));
}
__device__ __forceinline__ u32 soff(int row, int col) {   // 128-col single-chunk buffer
    return (u32)((row << 8) + (((col << 1)) ^ ((row & 15) << 4)));
}

// ---------------- pack weights into MFMA B-fragment order (+ zero counters) ----------------
// frag index f = (ntile*(K/16) + ks)*64 + lane; 16B at f*16.
// frag(lane) = W[k0 + ks*16 + (lane>>5)*8 + j][ntile*32 + (lane&31)], j=0..7
__global__ void pack_kernel(const float* __restrict__ W1, const float* __restrict__ W2,
                            const float* __restrict__ W3, const float* __restrict__ sW2,
                            const float* __restrict__ sW3,
                            __bf16* __restrict__ p1, __bf16* __restrict__ p2,
                            __bf16* __restrict__ p3, __bf16* __restrict__ ps2,
                            __bf16* __restrict__ ps3, int* __restrict__ cnt)
{
    if (blockIdx.x == 0 && threadIdx.x < 16) cnt[threadIdx.x] = 0;   // for scatter (next kernel)
    int bid = blockIdx.x;
    const float* src; __bf16* dst; int K, N, nt, kc;
    if (bid < 560)      { int c = bid / 80, r = bid % 80; nt = r / 10; kc = r % 10;
        src = W1 + (size_t)c * D_INc * Hc; dst = p1 + (size_t)c * Hc * D_INc; K = D_INc; N = Hc; }
    else if (bid < 784) { int b = bid - 560; int c = b / 32, r = b % 32; nt = r / 4; kc = r % 4;
        src = W2 + (size_t)c * Hc * Hc; dst = p2 + (size_t)c * Hc * Hc; K = Hc; N = Hc; }
    else if (bid < 1008){ int b = bid - 784; int c = b / 32, r = b % 32; nt = r / 4; kc = r % 4;
        src = W3 + (size_t)c * Hc * Hc; dst = p3 + (size_t)c * Hc * Hc; K = Hc; N = Hc; }
    else if (bid < 1016){ int r = bid - 1008; nt = r / 2; kc = r % 2; src = sW2; dst = ps2; K = D_SPDc; N = D_SPDc; }
    else                { int r = bid - 1016; nt = r / 2; kc = r % 2; src = sW3; dst = ps3; K = D_SPDc; N = D_SPDc; }
    int k0 = kc * 64, n0 = nt * 32;
    __shared__ float tile[64][33];
    int t = threadIdx.x;
    int col = t & 31, r8 = (t >> 5) * 8;
    #pragma unroll
    for (int i = 0; i < 8; ++i)
        tile[r8 + i][col] = src[(size_t)(k0 + r8 + i) * N + n0 + col];
    __syncthreads();
    int ksl = t >> 6, lane = t & 63, l31 = lane & 31, hi = lane >> 5;
    bf16x8 v;
    #pragma unroll
    for (int j = 0; j < 8; ++j) v[j] = (__bf16)tile[ksl * 16 + hi * 8 + j][l31];
    *(bf16x8*)(dst + ((size_t)(nt * (K / 16) + (k0 >> 4) + ksl) * 64 + lane) * 8) = v;
}

// ---------------- scatter rows into fixed per-branch regions (counts via fill atomics) -----
__global__ void scatter_kernel(const int* __restrict__ cmd, int* __restrict__ cnt,
                               int* __restrict__ rowlist)
{
    int i = blockIdx.x * 256 + threadIdx.x;   // 128 x 256 = 32768 exactly
    int lane = threadIdx.x & 63;
    int cv = cmd[i];
    #pragma unroll
    for (int c = 0; c < Cc; ++c) {
        unsigned long long m = __ballot(cv == c);
        if (!m) continue;
        int leader = __ffsll(m) - 1;
        int basep = 0;
        if (lane == leader) basep = atomicAdd(&cnt[c], (int)__popcll(m));
        basep = __shfl(basep, leader);
        if (cv == c) {
            int rank = (int)__popcll(m & ((1ull << lane) - 1ull));
            rowlist[c * B_N + basep + rank] = i;
        }
    }
}

// ---------------- main fused kernel: 32 rows/block, 4 waves (64 cols each) ----------------
__launch_bounds__(256, 3)
__global__ void branch_mlp_kernel(
    const float* __restrict__ rgb, const float* __restrict__ spd,
    const float* __restrict__ sW1, const float* __restrict__ sb1,
    const float* __restrict__ sb2, const float* __restrict__ sb3,
    const __bf16* __restrict__ ps2, const __bf16* __restrict__ ps3,
    const __bf16* __restrict__ p1, const __bf16* __restrict__ p2, const __bf16* __restrict__ p3,
    const float* __restrict__ b1, const float* __restrict__ b2, const float* __restrict__ b3,
    const float* __restrict__ hWb, const float* __restrict__ hbb,
    const float* __restrict__ hWs, const float* __restrict__ hbs,
    const float* __restrict__ hWt, const float* __restrict__ hbt,
    const int* __restrict__ cnt, const int* __restrict__ rowlist,
    float* __restrict__ out)
{
    __shared__ char xt[5 * 8192];          // 40 KB: x tile 32x640 bf16 (chunked-XOR); reused for act 32x256
    __shared__ char sbuf[8192];            // 8 KB: speed acts s1/s2 (32x128)
    __shared__ float headbuf[4][32][3];

    // flat block id -> (branch c, 32-row group g); Sum ceil(cnt/32) <= 1030 < grid 1031
    int bid = blockIdx.x;
    int c = -1, g = 0, accg = 0;
    #pragma unroll
    for (int i = 0; i < Cc; ++i) {
        int gc = (cnt[i] + 31) >> 5;
        if (c < 0 && bid < accg + gc) { c = i; g = bid - accg; }
        accg += gc;
    }
    if (c < 0) return;
    int n_c = cnt[c];
    const int* rl = rowlist + c * B_N;

    int tid = threadIdx.x, wave = tid >> 6, lane = tid & 63, l31 = lane & 31, hi = lane >> 5;

    // hoisted per-lane constants (L2-resident, independent of all phases)
    int col0 = wave * 64 + l31, col1 = col0 + 32;
    float bv1a = b1[c * Hc + col0], bv1b = b1[c * Hc + col1];
    float bv2a = b2[c * Hc + col0], bv2b = b2[c * Hc + col1];
    float bv3a = b3[c * Hc + col0], bv3b = b3[c * Hc + col1];
    float wbA = hWb[c * Hc + col0], wbB = hWb[c * Hc + col1];
    float wsA = hWs[c * Hc + col0], wsB = hWs[c * Hc + col1];
    float wtA = hWt[c * Hc + col0], wtB = hWt[c * Hc + col1];
    float sb2v = sb2[wave * 32 + l31], sb3v = sb3[wave * 32 + l31];

    // staging identity: thread handles row r_st, col-slice sub*8 + i*64
    int r_st = tid >> 3, sub = tid & 7;
    int gg = g * 32 + r_st;
    int rid_st = rl[gg < n_c ? gg : n_c - 1];          // clamped dup for tail
    float sv = spd[rid_st];

    // phase 0: s1 = tanh(spd*sW1 + sb1) -> sbuf[32][128]
    {
        int j0 = sub * 16;
        #pragma unroll
        for (int jj = 0; jj < 16; ++jj) {
            int j = j0 + jj;
            *(__bf16*)(sbuf + soff(r_st, j)) = (__bf16)tanhf_(sv * sW1[j] + sb1[j]);
        }
    }
    __syncthreads();

    f32x16 sacc;

    // phase 1: s2 = tanh(s1 @ sW2); wave computes cols wave*32..+31 (K=128)
    #pragma unroll
    for (int j = 0; j < 16; ++j) sacc[j] = 0.f;
    {
        const __bf16* pw = ps2 + ((size_t)(wave * 8) * 64 + lane) * 8;
        #pragma unroll
        for (int ks = 0; ks < 8; ++ks) {
            bf16x8 a = *(const bf16x8*)(sbuf + soff(l31, ks * 16 + hi * 8));
            bf16x8 b = *(const bf16x8*)(pw + (size_t)ks * 512);
            sacc = __builtin_amdgcn_mfma_f32_32x32x16_bf16(a, b, sacc, 0, 0, 0);
        }
    }
    __syncthreads();                                   // all s1 reads done
    {
        int col = wave * 32 + l31;
        #pragma unroll
        for (int rg = 0; rg < 16; ++rg) {
            int row = (rg & 3) + 8 * (rg >> 2) + 4 * hi;
            *(__bf16*)(sbuf + soff(row, col)) = (__bf16)tanhf_(sacc[rg] + sb2v);
        }
    }
    __syncthreads();

    // phase 2: s3 = tanh(s2 @ sW3) -> xt cols 512..639 (chunk 4)
    #pragma unroll
    for (int j = 0; j < 16; ++j) sacc[j] = 0.f;
    {
        const __bf16* pw = ps3 + ((size_t)(wave * 8) * 64 + lane) * 8;
        #pragma unroll
        for (int ks = 0; ks < 8; ++ks) {
            bf16x8 a = *(const bf16x8*)(sbuf + soff(l31, ks * 16 + hi * 8));
            bf16x8 b = *(const bf16x8*)(pw + (size_t)ks * 512);
            sacc = __builtin_amdgcn_mfma_f32_32x32x16_bf16(a, b, sacc, 0, 0, 0);
        }
    }
    {
        int col = wave * 32 + l31;
        #pragma unroll
        for (int rg = 0; rg < 16; ++rg) {
            int row = (rg & 3) + 8 * (rg >> 2) + 4 * hi;
            *(__bf16*)(xt + xoff(row, 512 + col)) = (__bf16)tanhf_(sacc[rg] + sb3v);
        }
    }

    // staging: rgb f32 -> bf16 into xt chunks 0..3, coalesced (8 lanes/row, 256B segments)
    {
        const float* rr = rgb + (size_t)rid_st * D_RGBc + sub * 8;
        #pragma unroll
        for (int i = 0; i < 8; ++i) {
            f32x4 v0 = *(const f32x4*)(rr + i * 64);
            f32x4 v1 = *(const f32x4*)(rr + i * 64 + 4);
            bf16x8 o;
            #pragma unroll
            for (int j = 0; j < 4; ++j) { o[j] = (__bf16)v0[j]; o[4 + j] = (__bf16)v1[j]; }
            *(bf16x8*)(xt + xoff(r_st, i * 64 + sub * 8)) = o;
        }
    }
    __syncthreads();                                   // full x tile ready

    f32x16 acc0, acc1;
    #pragma unroll
    for (int j = 0; j < 16; ++j) { acc0[j] = 0.f; acc1[j] = 0.f; }

    // layer 1: K=640 from LDS x tile; B streamed (fragment-packed, coalesced)
    {
        const __bf16* pb = p1 + (size_t)c * Hc * D_INc;
        const __bf16* pw0 = pb + ((size_t)((2 * wave) * 40) * 64 + lane) * 8;
        const __bf16* pw1 = pb + ((size_t)((2 * wave + 1) * 40) * 64 + lane) * 8;
        #pragma unroll 8
        for (int ks = 0; ks < 40; ++ks) {
            bf16x8 a  = *(const bf16x8*)(xt + xoff(l31, ks * 16 + hi * 8));
            bf16x8 b0 = *(const bf16x8*)(pw0 + (size_t)ks * 512);
            bf16x8 b1v = *(const bf16x8*)(pw1 + (size_t)ks * 512);
            acc0 = __builtin_amdgcn_mfma_f32_32x32x16_bf16(a, b0, acc0, 0, 0, 0);
            acc1 = __builtin_amdgcn_mfma_f32_32x32x16_bf16(a, b1v, acc1, 0, 0, 0);
        }
    }
    __syncthreads();                                   // x tile dead; reuse chunks 0-1 for act
    #pragma unroll
    for (int nt = 0; nt < 2; ++nt) {
        int col = wave * 64 + nt * 32 + l31;
        float bv = nt ? bv1b : bv1a;
        const f32x16& a = nt ? acc1 : acc0;
        #pragma unroll
        for (int rg = 0; rg < 16; ++rg) {
            int row = (rg & 3) + 8 * (rg >> 2) + 4 * hi;
            *(__bf16*)(xt + xoff(row, col)) = (__bf16)sigmoidf_(a[rg] + bv);
        }
    }
    __syncthreads();

    // layer 2: K=256
    #pragma unroll
    for (int j = 0; j < 16; ++j) { acc0[j] = 0.f; acc1[j] = 0.f; }
    {
        const __bf16* pb = p2 + (size_t)c * Hc * Hc;
        const __bf16* pw0 = pb + ((size_t)((2 * wave) * 16) * 64 + lane) * 8;
        const __bf16* pw1 = pb + ((size_t)((2 * wave + 1) * 16) * 64 + lane) * 8;
        #pragma unroll
        for (int ks = 0; ks < 16; ++ks) {
            bf16x8 a  = *(const bf16x8*)(xt + xoff(l31, ks * 16 + hi * 8));
            bf16x8 b0 = *(const bf16x8*)(pw0 + (size_t)ks * 512);
            bf16x8 b1v = *(const bf16x8*)(pw1 + (size_t)ks * 512);
            acc0 = __builtin_amdgcn_mfma_f32_32x32x16_bf16(a, b0, acc0, 0, 0, 0);
            acc1 = __builtin_amdgcn_mfma_f32_32x32x16_bf16(a, b1v, acc1, 0, 0, 0);
        }
    }
    __syncthreads();
    #pragma unroll
    for (int nt = 0; nt < 2; ++nt) {
        int col = wave * 64 + nt * 32 + l31;
        float bv = nt ? bv2b : bv2a;
        const f32x16& a = nt ? acc1 : acc0;
        #pragma unroll
        for (int rg = 0; rg < 16; ++rg) {
            int row = (rg & 3) + 8 * (rg >> 2) + 4 * hi;
            *(__bf16*)(xt + xoff(row, col)) = (__bf16)sigmoidf_(a[rg] + bv);
        }
    }
    __syncthreads();

    // layer 3 (stays in regs) + heads
    #pragma unroll
    for (int j = 0; j < 16; ++j) { acc0[j] = 0.f; acc1[j] = 0.f; }
    {
        const __bf16* pb = p3 + (size_t)c * Hc * Hc;
        const __bf16* pw0 = pb + ((size_t)((2 * wave) * 16) * 64 + lane) * 8;
        const __bf16* pw1 = pb + ((size_t)((2 * wave + 1) * 16) * 64 + lane) * 8;
        #pragma unroll
        for (int ks = 0; ks < 16; ++ks) {
            bf16x8 a  = *(const bf16x8*)(xt + xoff(l31, ks * 16 + hi * 8));
            bf16x8 b0 = *(const bf16x8*)(pw0 + (size_t)ks * 512);
            bf16x8 b1v = *(const bf16x8*)(pw1 + (size_t)ks * 512);
            acc0 = __builtin_amdgcn_mfma_f32_32x32x16_bf16(a, b0, acc0, 0, 0, 0);
            acc1 = __builtin_amdgcn_mfma_f32_32x32x16_bf16(a, b1v, acc1, 0, 0, 0);
        }
    }

    float pr[3][16];
    #pragma unroll
    for (int hd = 0; hd < 3; ++hd)
        #pragma unroll
        for (int rg = 0; rg < 16; ++rg) pr[hd][rg] = 0.f;
    #pragma unroll
    for (int nt = 0; nt < 2; ++nt) {
        float bv = nt ? bv3b : bv3a;
        float wb = nt ? wbB : wbA, wsv = nt ? wsB : wsA, wtv = nt ? wtB : wtA;
        const f32x16& a = nt ? acc1 : acc0;
        #pragma unroll
        for (int rg = 0; rg < 16; ++rg) {
            float h = sigmoidf_(a[rg] + bv);
            pr[0][rg] += h * wb;
            pr[1][rg] += h * wsv;
            pr[2][rg] += h * wtv;
        }
    }
    #pragma unroll
    for (int m = 1; m < 32; m <<= 1)
        #pragma unroll
        for (int hd = 0; hd < 3; ++hd)
            #pragma unroll
            for (int rg = 0; rg < 16; ++rg)
                pr[hd][rg] += __shfl_xor(pr[hd][rg], m);   // reduce over l31 (within 32-half)
    if (l31 == 0) {
        #pragma unroll
        for (int rg = 0; rg < 16; ++rg) {
            int row = (rg & 3) + 8 * (rg >> 2) + 4 * hi;
            headbuf[wave][row][0] = pr[0][rg];
            headbuf[wave][row][1] = pr[1][rg];
            headbuf[wave][row][2] = pr[2][rg];
        }
    }
    __syncthreads();
    if (tid < 96) {
        int row = tid / 3, hd = tid % 3;
        int g2 = g * 32 + row;
        if (g2 < n_c) {
            int R = rl[g2];
            float v = headbuf[0][row][hd] + headbuf[1][row][hd] + headbuf[2][row][hd] + headbuf[3][row][hd];
            if (hd == 0)      out[R]           = sigmoidf_(v + hbb[c]);
            else if (hd == 1) out[B_N + R]     = tanhf_(v + hbs[c]);
            else              out[2 * B_N + R] = sigmoidf_(v + hbt[c]);
        }
    }
}

extern "C" void kernel_launch(void* const* d_in, const int* in_sizes, int n_in,
                              void* d_out, int out_size, void* d_ws, size_t ws_size,
                              hipStream_t stream)
{
    const float* rgb = (const float*)d_in[0];
    const float* spd = (const float*)d_in[1];
    const int*   cmd = (const int*)d_in[2];
    const float* sW1 = (const float*)d_in[3];
    const float* sb1 = (const float*)d_in[4];
    const float* sW2 = (const float*)d_in[5];
    const float* sb2 = (const float*)d_in[6];
    const float* sW3 = (const float*)d_in[7];
    const float* sb3 = (const float*)d_in[8];
    const float* W1  = (const float*)d_in[9];
    const float* b1  = (const float*)d_in[10];
    const float* W2  = (const float*)d_in[11];
    const float* b2  = (const float*)d_in[12];
    const float* W3  = (const float*)d_in[13];
    const float* b3  = (const float*)d_in[14];
    const float* hWb = (const float*)d_in[15];
    const float* hbb = (const float*)d_in[16];
    const float* hWs = (const float*)d_in[17];
    const float* hbs = (const float*)d_in[18];
    const float* hWt = (const float*)d_in[19];
    const float* hbt = (const float*)d_in[20];

    char* ws = (char*)d_ws;
    size_t off = 0;
    auto take = [&](size_t bytes) { char* p = ws + off; off = (off + bytes + 255) & ~(size_t)255; return p; };
    __bf16* p1  = (__bf16*)take((size_t)Cc * Hc * D_INc * 2);
    __bf16* p2  = (__bf16*)take((size_t)Cc * Hc * Hc * 2);
    __bf16* p3  = (__bf16*)take((size_t)Cc * Hc * Hc * 2);
    __bf16* ps2 = (__bf16*)take((size_t)D_SPDc * D_SPDc * 2);
    __bf16* ps3 = (__bf16*)take((size_t)D_SPDc * D_SPDc * 2);
    int* rowlist = (int*)take((size_t)Cc * B_N * 4);   // fixed per-branch regions
    int* cnt     = (int*)take(16 * 4);

    pack_kernel<<<1024, 256, 0, stream>>>(W1, W2, W3, sW2, sW3, p1, p2, p3, ps2, ps3, cnt);
    scatter_kernel<<<128, 256, 0, stream>>>(cmd, cnt, rowlist);
    branch_mlp_kernel<<<1031, 256, 0, stream>>>(rgb, spd, sW1, sb1, sb2, sb3,
        ps2, ps3, p1, p2, p3, b1, b2, b3,
        hWb, hbb, hWs, hbs, hWt, hbt, cnt, rowlist, (float*)d_out);
}